// Round 1
// baseline (105.191 us; speedup 1.0000x reference)
//
#include <hip/hip_runtime.h>

// NCEAverage: out[b,k] = exp(dot(memory[idx'[b,k]], x[b]) / T) / Z
//   idx'[b,0] = y[b], idx'[b,k>0] = idx[b,k]
//   Z = mean(e) * OUTPUT_SIZE
// Shapes: x (256,128) f32, y (256,) int, idx (256,4097) int, memory (1281167,128) f32
// out (256,4097) f32.

constexpr int   kB        = 256;
constexpr int   kKp1      = 4097;      // K+1
constexpr long long kOutRows = 1281167LL;
constexpr int   kSplits   = 8;         // blocks per batch row
constexpr int   kMainBlocks = kB * kSplits;  // 2048
constexpr int   kThreads  = 256;
constexpr float kInvT     = 1.0f / 0.07f;

// --- kernel 1: gather rows, dot with x[b], exp, write e; per-block partial sum ---
__global__ __launch_bounds__(kThreads) void nce_main(
    const float* __restrict__ x, const int* __restrict__ y,
    const int* __restrict__ idx, const float* __restrict__ memory,
    float* __restrict__ out, float* __restrict__ blksum)
{
    const int b     = blockIdx.x / kSplits;
    const int chunk = blockIdx.x % kSplits;
    const int tid   = threadIdx.x;
    const int wave  = tid >> 6;
    const int lane  = tid & 63;
    const int half  = lane >> 5;       // which 32-lane group
    const int dlane = lane & 31;       // lane within group: covers d = 4*dlane..4*dlane+3
    const int slot  = wave * 2 + half; // 0..7 row-slots per block iteration

    // x[b] as 32 float4 per 32-lane group (held in registers for the whole block)
    const float4* x4 = reinterpret_cast<const float4*>(x) + (size_t)b * 32;
    const float4  xv = x4[dlane];

    const float4* m4   = reinterpret_cast<const float4*>(memory);
    const int*    idxb = idx + (size_t)b * kKp1;
    float*        outb = out + (size_t)b * kKp1;

    const int per = (kKp1 + kSplits - 1) / kSplits;  // 513
    const int k0  = chunk * per;
    const int k1  = (k0 + per < kKp1) ? (k0 + per) : kKp1;

    float acc = 0.0f;
    for (int k = k0 + slot; k < k1; k += 8) {
        const int row = (k == 0) ? y[b] : idxb[k];
        const float4 mv = m4[(size_t)row * 32 + dlane];
        float dot = mv.x * xv.x + mv.y * xv.y + mv.z * xv.z + mv.w * xv.w;
        // butterfly reduce across the 32-lane group (masks < 32 stay in-group)
        #pragma unroll
        for (int m = 16; m >= 1; m >>= 1)
            dot += __shfl_xor(dot, m, 64);
        const float e = __expf(dot * kInvT);
        if (dlane == 0) {
            outb[k] = e;
            acc += e;
        }
    }

    // block reduction of acc -> blksum[blockIdx.x]
    #pragma unroll
    for (int m = 32; m >= 1; m >>= 1)
        acc += __shfl_xor(acc, m, 64);
    __shared__ float red[kThreads / 64];
    if (lane == 0) red[wave] = acc;
    __syncthreads();
    if (tid == 0)
        blksum[blockIdx.x] = red[0] + red[1] + red[2] + red[3];
}

// --- kernel 2: reduce partial sums -> scale = (B*(K+1)/OUT_ROWS) / sum ---
__global__ __launch_bounds__(256) void nce_scale(float* __restrict__ blksum)
{
    float s = 0.0f;
    for (int i = threadIdx.x; i < kMainBlocks; i += 256) s += blksum[i];
    #pragma unroll
    for (int m = 32; m >= 1; m >>= 1)
        s += __shfl_xor(s, m, 64);
    __shared__ float red[4];
    const int wave = threadIdx.x >> 6;
    if ((threadIdx.x & 63) == 0) red[wave] = s;
    __syncthreads();
    if (threadIdx.x == 0) {
        const float tot = red[0] + red[1] + red[2] + red[3];
        // out = e / Z, Z = tot / (B*(K+1)) * OUT_ROWS
        const float scale = ((float)(kB * kKp1) / (float)kOutRows) / tot;
        blksum[kMainBlocks] = scale;
    }
}

// --- kernel 3: out *= scale (float4) ---
__global__ __launch_bounds__(256) void nce_norm(
    float4* __restrict__ out4, const float* __restrict__ scalep, int n4)
{
    const float sc = scalep[0];
    int i = blockIdx.x * blockDim.x + threadIdx.x;
    const int stride = gridDim.x * blockDim.x;
    for (; i < n4; i += stride) {
        float4 v = out4[i];
        v.x *= sc; v.y *= sc; v.z *= sc; v.w *= sc;
        out4[i] = v;
    }
}

extern "C" void kernel_launch(void* const* d_in, const int* in_sizes, int n_in,
                              void* d_out, int out_size, void* d_ws, size_t ws_size,
                              hipStream_t stream) {
    const float* x      = (const float*)d_in[0];
    const int*   y      = (const int*)d_in[1];
    const int*   idx    = (const int*)d_in[2];
    const float* memory = (const float*)d_in[3];
    float*       out    = (float*)d_out;
    float*       blksum = (float*)d_ws;   // kMainBlocks partials + 1 scale slot

    hipLaunchKernelGGL(nce_main, dim3(kMainBlocks), dim3(kThreads), 0, stream,
                       x, y, idx, memory, out, blksum);
    hipLaunchKernelGGL(nce_scale, dim3(1), dim3(256), 0, stream, blksum);
    hipLaunchKernelGGL(nce_norm, dim3(1024), dim3(256), 0, stream,
                       (float4*)d_out, blksum + kMainBlocks, out_size / 4);
}

// Round 2
// 91.214 us; speedup vs baseline: 1.1532x; 1.1532x over previous
//
#include <hip/hip_runtime.h>

// NCEAverage: out[b,k] = exp(dot(memory[idx'[b,k]], x[b]) / T) / Z
//   idx'[b,0] = y[b], idx'[b,k>0] = idx[b,k]
//   Z = mean(e) * OUTPUT_SIZE
// x (256,128) f32, y (256,) int, idx (256,4097) int, memory (1281167,128) f32
// out (256,4097) f32.

constexpr int   kB          = 256;
constexpr int   kKp1        = 4097;        // K+1
constexpr long long kOutRows = 1281167LL;
constexpr int   kSplits     = 8;           // blocks per batch row
constexpr int   kMainBlocks = kB * kSplits;   // 2048 (= exactly full residency)
constexpr int   kThreads    = 256;
constexpr float kInvT       = 1.0f / 0.07f;

__device__ __forceinline__ float dot4(float4 a, float4 b) {
    return a.x * b.x + a.y * b.y + a.z * b.z + a.w * b.w;
}

// --- kernel 1: gather rows, dot with x[b], exp, write e; per-block partial sum.
// Each 32-lane group owns 4 consecutive k per iteration -> 4 gathers in flight.
__global__ __launch_bounds__(kThreads) void nce_main(
    const float* __restrict__ x, const int* __restrict__ y,
    const int* __restrict__ idx, const float* __restrict__ memory,
    float* __restrict__ out, float* __restrict__ blksum)
{
    const int b     = blockIdx.x >> 3;
    const int chunk = blockIdx.x & 7;
    const int tid   = threadIdx.x;
    const int wave  = tid >> 6;
    const int lane  = tid & 63;
    const int half  = lane >> 5;
    const int dlane = lane & 31;          // covers d = 4*dlane..4*dlane+3
    const int g     = wave * 2 + half;    // 0..7 groups per block

    const float4 xv = reinterpret_cast<const float4*>(x)[b * 32 + dlane];
    const float4* m4   = reinterpret_cast<const float4*>(memory);
    const int*    idxb = idx + (size_t)b * kKp1;
    float*        outb = out + (size_t)b * kKp1;
    const int     ypos = y[b];

    const int per = (kKp1 + kSplits - 1) / kSplits;   // 513
    const int k0  = chunk * per;
    const int k1  = (k0 + per < kKp1) ? (k0 + per) : kKp1;

    float acc = 0.0f;
    for (int kb = k0 + g * 4; kb < k1; kb += 32) {
        const int krem = k1 - kb;                     // >= 1
        // 4 row indices (uniform within the 32-lane group); OOB -> row 0 (safe)
        const int r0 = (kb == 0) ? ypos : idxb[kb];
        const int r1 = (krem > 1) ? idxb[kb + 1] : 0;
        const int r2 = (krem > 2) ? idxb[kb + 2] : 0;
        const int r3 = (krem > 3) ? idxb[kb + 3] : 0;
        // 4 independent 512B row gathers in flight
        const float4 a0 = m4[(size_t)r0 * 32 + dlane];
        const float4 a1 = m4[(size_t)r1 * 32 + dlane];
        const float4 a2 = m4[(size_t)r2 * 32 + dlane];
        const float4 a3 = m4[(size_t)r3 * 32 + dlane];
        float d0 = dot4(a0, xv), d1 = dot4(a1, xv);
        float d2 = dot4(a2, xv), d3 = dot4(a3, xv);
        // 4 interleaved (independent) butterfly reduces across the 32-lane group
        #pragma unroll
        for (int m = 16; m >= 1; m >>= 1) {
            d0 += __shfl_xor(d0, m, 64);
            d1 += __shfl_xor(d1, m, 64);
            d2 += __shfl_xor(d2, m, 64);
            d3 += __shfl_xor(d3, m, 64);
        }
        if (dlane == 0) {
            const float e0 = __expf(d0 * kInvT);
            const float e1 = __expf(d1 * kInvT);
            const float e2 = __expf(d2 * kInvT);
            const float e3 = __expf(d3 * kInvT);
            outb[kb] = e0;  acc += e0;
            if (krem > 1) { outb[kb + 1] = e1; acc += e1; }
            if (krem > 2) { outb[kb + 2] = e2; acc += e2; }
            if (krem > 3) { outb[kb + 3] = e3; acc += e3; }
        }
    }

    // block reduction of acc -> blksum[blockIdx.x]
    #pragma unroll
    for (int m = 32; m >= 1; m >>= 1)
        acc += __shfl_xor(acc, m, 64);
    __shared__ float red[kThreads / 64];
    if (lane == 0) red[wave] = acc;
    __syncthreads();
    if (tid == 0)
        blksum[blockIdx.x] = red[0] + red[1] + red[2] + red[3];
}

// --- kernel 2: every block redundantly reduces the 2048 partials (fixed order
// -> bit-identical scale in all blocks), then scales its chunk of out.
__global__ __launch_bounds__(256) void nce_norm(
    float4* __restrict__ out4, const float* __restrict__ blksum, int n4)
{
    float s = 0.0f;
    for (int i = threadIdx.x; i < kMainBlocks; i += 256) s += blksum[i];
    #pragma unroll
    for (int m = 32; m >= 1; m >>= 1)
        s += __shfl_xor(s, m, 64);
    __shared__ float red[4];
    if ((threadIdx.x & 63) == 0) red[threadIdx.x >> 6] = s;
    __syncthreads();
    const float tot = red[0] + red[1] + red[2] + red[3];
    // out = e / Z, Z = tot / (B*(K+1)) * OUT_ROWS
    const float sc = ((float)(kB * kKp1) / (float)kOutRows) / tot;

    int i = blockIdx.x * blockDim.x + threadIdx.x;
    const int stride = gridDim.x * blockDim.x;
    for (; i < n4; i += stride) {
        float4 v = out4[i];
        v.x *= sc; v.y *= sc; v.z *= sc; v.w *= sc;
        out4[i] = v;
    }
}

extern "C" void kernel_launch(void* const* d_in, const int* in_sizes, int n_in,
                              void* d_out, int out_size, void* d_ws, size_t ws_size,
                              hipStream_t stream) {
    const float* x      = (const float*)d_in[0];
    const int*   y      = (const int*)d_in[1];
    const int*   idx    = (const int*)d_in[2];
    const float* memory = (const float*)d_in[3];
    float*       out    = (float*)d_out;
    float*       blksum = (float*)d_ws;   // kMainBlocks partials

    hipLaunchKernelGGL(nce_main, dim3(kMainBlocks), dim3(kThreads), 0, stream,
                       x, y, idx, memory, out, blksum);
    hipLaunchKernelGGL(nce_norm, dim3(1024), dim3(256), 0, stream,
                       (float4*)d_out, blksum, out_size / 4);
}